// Round 3
// baseline (923.563 us; speedup 1.0000x reference)
//
#include <hip/hip_runtime.h>
#include <stdint.h>

typedef __attribute__((ext_vector_type(8))) short short8;
typedef __attribute__((ext_vector_type(4))) float float4v;
typedef __attribute__((ext_vector_type(4))) unsigned int uint4v;

#define NSEQ   4096
#define DMODEL 1024
#define NHEAD  16
#define DK     64
#define NP     512
#define MTOT   4608
#define CHUNK  576
#define NCHUNK 8
#define SCALE  2.8284271247461903f   // 64^0.25

__device__ __forceinline__ float b2f(unsigned short u) {
  union { unsigned u; float f; } x; x.u = ((unsigned)u) << 16; return x.f;
}
__device__ __forceinline__ unsigned short f2b(float f) {
  union { float f; unsigned u; } x; x.f = f;
  unsigned r = x.u + 0x7fffu + ((x.u >> 16) & 1u);
  return (unsigned short)(r >> 16);
}
__device__ __forceinline__ void split1(float x, unsigned short& h, unsigned short& l) {
  h = f2b(x);
  l = f2b(x - b2f(h));
}
__device__ __forceinline__ void gload16(const void* g, void* l) {
  __builtin_amdgcn_global_load_lds((const __attribute__((address_space(1))) void*)g,
                                   (__attribute__((address_space(3))) void*)l,
                                   16, 0, 0);
}

// ---------------- weight f32 -> (hi, lo) bf16 split
__global__ __launch_bounds__(256) void cvt_split(const float* __restrict__ s,
                                                 unsigned short* __restrict__ hi,
                                                 unsigned short* __restrict__ lo, int n) {
  const int i = (blockIdx.x * 256 + threadIdx.x) * 8;
  if (i + 8 > n) return;
  float4v x0 = *(const float4v*)(s + i);
  float4v x1 = *(const float4v*)(s + i + 4);
  unsigned short h[8], l[8];
#pragma unroll
  for (int j = 0; j < 4; ++j) split1(x0[j], h[j], l[j]);
#pragma unroll
  for (int j = 0; j < 4; ++j) split1(x1[j], h[4 + j], l[4 + j]);
  uint4v ph, pl;
#pragma unroll
  for (int j = 0; j < 4; ++j) {
    ph[j] = (unsigned)h[2 * j] | ((unsigned)h[2 * j + 1] << 16);
    pl[j] = (unsigned)l[2 * j] | ((unsigned)l[2 * j + 1] << 16);
  }
  *(uint4v*)(hi + i) = ph;
  *(uint4v*)(lo + i) = pl;
}

// ---------------- split GEMM: C[M,N](f32) = A[M,K](f32) @ B[N,K]^T, B pre-split hi/lo.
// 3-term hi/lo product: near-f32 precision. 128x128 tile, BK=32, 4 waves.
__global__ __launch_bounds__(256, 2) void gemm_split(const float* __restrict__ A,
                                                     const unsigned short* __restrict__ Bh,
                                                     const unsigned short* __restrict__ Bl,
                                                     float* __restrict__ C,
                                                     int M, int N, int K) {
  __shared__ unsigned short Ash[4096], Asl[4096], Bsh[4096], Bsl[4096];
  const int tid = threadIdx.x;
  const int w = tid >> 6, lane = tid & 63;
  const int wr = w >> 1, wc = w & 1;
  const long brow = (long)blockIdx.y * 128;
  const long bcol = (long)blockIdx.x * 128;

  const int rowA0 = w * 16 + (lane >> 2);
  const int colk  = (lane & 3) * 8;
  const float* Ag0 = A + (brow + rowA0) * (long)K + colk;
  const float* Ag1 = Ag0 + 64L * K;
  unsigned short* Ah0 = &Ash[tid * 8];
  unsigned short* Ah1 = &Ash[2048 + tid * 8];
  unsigned short* Al0 = &Asl[tid * 8];
  unsigned short* Al1 = &Asl[2048 + tid * 8];

  const int r0 = tid >> 2;
  const int kc = (tid & 3) * 8;
  const unsigned short* Bhg0 = Bh + (bcol + r0) * (long)K + kc;
  const unsigned short* Bhg1 = Bhg0 + 64L * K;
  const unsigned short* Blg0 = Bl + (bcol + r0) * (long)K + kc;
  const unsigned short* Blg1 = Blg0 + 64L * K;
  unsigned short* Bh0 = &Bsh[w * 512];
  unsigned short* Bl0 = &Bsl[w * 512];

  float4v acc[4][4];
#pragma unroll
  for (int i = 0; i < 4; ++i)
#pragma unroll
    for (int j = 0; j < 4; ++j) acc[i][j] = (float4v){0.f, 0.f, 0.f, 0.f};

  const int m15 = lane & 15, q8 = (lane >> 4) * 8;

  for (int k0 = 0; k0 < K; k0 += 32) {
    gload16(Bhg0 + k0, Bh0);
    gload16(Bhg1 + k0, Bh0 + 2048);
    gload16(Blg0 + k0, Bl0);
    gload16(Blg1 + k0, Bl0 + 2048);
    {
      float4v a0 = *(const float4v*)(Ag0 + k0);
      float4v a1 = *(const float4v*)(Ag0 + k0 + 4);
      float4v c0 = *(const float4v*)(Ag1 + k0);
      float4v c1 = *(const float4v*)(Ag1 + k0 + 4);
      unsigned short h[16], l[16];
#pragma unroll
      for (int j = 0; j < 4; ++j) { split1(a0[j], h[j], l[j]); split1(a1[j], h[4 + j], l[4 + j]); }
#pragma unroll
      for (int j = 0; j < 4; ++j) { split1(c0[j], h[8 + j], l[8 + j]); split1(c1[j], h[12 + j], l[12 + j]); }
      uint4v pah, pal, pch, pcl;
#pragma unroll
      for (int j = 0; j < 4; ++j) {
        pah[j] = (unsigned)h[2 * j] | ((unsigned)h[2 * j + 1] << 16);
        pal[j] = (unsigned)l[2 * j] | ((unsigned)l[2 * j + 1] << 16);
        pch[j] = (unsigned)h[8 + 2 * j] | ((unsigned)h[8 + 2 * j + 1] << 16);
        pcl[j] = (unsigned)l[8 + 2 * j] | ((unsigned)l[8 + 2 * j + 1] << 16);
      }
      *(uint4v*)Ah0 = pah; *(uint4v*)Al0 = pal;
      *(uint4v*)Ah1 = pch; *(uint4v*)Al1 = pcl;
    }
    __syncthreads();
    short8 ah[4], al[4], bh[4], bl[4];
#pragma unroll
    for (int t = 0; t < 4; ++t) {
      const int ar = (wr * 64 + t * 16 + m15) * 32 + q8;
      const int br = (wc * 64 + t * 16 + m15) * 32 + q8;
      ah[t] = *(const short8*)&Ash[ar];
      al[t] = *(const short8*)&Asl[ar];
      bh[t] = *(const short8*)&Bsh[br];
      bl[t] = *(const short8*)&Bsl[br];
    }
#pragma unroll
    for (int mt = 0; mt < 4; ++mt)
#pragma unroll
      for (int nt = 0; nt < 4; ++nt) {
        acc[mt][nt] = __builtin_amdgcn_mfma_f32_16x16x32_bf16(ah[mt], bh[nt], acc[mt][nt], 0, 0, 0);
        acc[mt][nt] = __builtin_amdgcn_mfma_f32_16x16x32_bf16(al[mt], bh[nt], acc[mt][nt], 0, 0, 0);
        acc[mt][nt] = __builtin_amdgcn_mfma_f32_16x16x32_bf16(ah[mt], bl[nt], acc[mt][nt], 0, 0, 0);
      }
    __syncthreads();
  }

  const long col  = bcol + wc * 64 + m15;
  const long rowb = brow + wr * 64 + (lane >> 4) * 4;
#pragma unroll
  for (int mt = 0; mt < 4; ++mt)
#pragma unroll
    for (int nt = 0; nt < 4; ++nt)
#pragma unroll
      for (int i = 0; i < 4; ++i)
        C[(rowb + mt * 16 + i) * (long)N + col + nt * 16] = acc[mt][nt][i];
}

// ---------------- P1: per-(b,h,d) online max/sumexp over m-chunk (f32 k).
__global__ __launch_bounds__(256) void col_stats(const float* __restrict__ kf,
                                                 const float* __restrict__ MK,
                                                 float* __restrict__ pmax,
                                                 float* __restrict__ psum) {
  const int bh = blockIdx.x, c = blockIdx.y;
  const int b = bh >> 4, h = bh & 15;
  const int d = threadIdx.x & 63, g = threadIdx.x >> 6;
  float mx = -1e30f, sm = 0.f;
  const int m0 = c * CHUNK;
  for (int i = g; i < CHUNK; i += 4) {
    const int m = m0 + i;
    float val;
    if (m < NSEQ) val = kf[((long)(b * NSEQ + m)) * DMODEL + h * DK + d];
    else          val = MK[((long)h * NP + (m - NSEQ)) * DK + d];
    const float x = val * SCALE;
    if (x > mx) { sm = sm * __expf(mx - x) + 1.f; mx = x; }
    else        { sm += __expf(x - mx); }
  }
  __shared__ float smx[4][64], ssm[4][64];
  smx[g][d] = mx; ssm[g][d] = sm;
  __syncthreads();
  if (g == 0) {
    float M = smx[0][d], S = ssm[0][d];
#pragma unroll
    for (int j = 1; j < 4; ++j) {
      const float m2 = smx[j][d], s2 = ssm[j][d];
      const float nm = fmaxf(M, m2);
      S = S * __expf(M - nm) + s2 * __expf(m2 - nm);
      M = nm;
    }
    pmax[(bh * NCHUNK + c) * 64 + d] = M;
    psum[(bh * NCHUNK + c) * 64 + d] = S;
  }
}

// ---------------- P2: combine chunk stats.
__global__ __launch_bounds__(256) void combine_stats(const float* __restrict__ pmax,
                                                     const float* __restrict__ psum,
                                                     float* __restrict__ gmax,
                                                     float* __restrict__ gZ) {
  const int idx = blockIdx.x * 256 + threadIdx.x;
  const int bh = idx >> 6, d = idx & 63;
  float M = -1e30f, S = 0.f;
#pragma unroll
  for (int c = 0; c < NCHUNK; ++c) {
    const float m2 = pmax[(bh * NCHUNK + c) * 64 + d];
    const float s2 = psum[(bh * NCHUNK + c) * 64 + d];
    const float nm = fmaxf(M, m2);
    S = S * __expf(M - nm) + s2 * __expf(m2 - nm);
    M = nm;
  }
  gmax[idx] = M;
  gZ[idx] = S;
}

// ---------------- P3: partial kv over chunk (f32 k, f32 v).
__global__ __launch_bounds__(256) void partial_kv(const float* __restrict__ kf,
                                                  const float* __restrict__ vf,
                                                  const float* __restrict__ MK,
                                                  const float* __restrict__ MV,
                                                  const float* __restrict__ gmax,
                                                  float* __restrict__ pkv) {
  const int bh = blockIdx.x, c = blockIdx.y;
  const int b = bh >> 4, h = bh & 15;
  const int e = threadIdx.x & 63, dg = threadIdx.x >> 6;
  __shared__ float E[16][64], Vv[16][64];
  float acc[16];
#pragma unroll
  for (int j = 0; j < 16; ++j) acc[j] = 0.f;
  const int cc = e;
  const float gm = gmax[bh * 64 + cc];

  for (int t = 0; t < CHUNK / 16; ++t) {
    const int mt0 = c * CHUNK + t * 16;
#pragma unroll
    for (int i = 0; i < 4; ++i) {
      const int r = dg + 4 * i;
      const int m = mt0 + r;
      float kvv, vvv;
      if (m < NSEQ) {
        const long base = ((long)(b * NSEQ + m)) * DMODEL + h * DK + cc;
        kvv = kf[base];
        vvv = vf[base];
      } else {
        const long base = ((long)h * NP + (m - NSEQ)) * DK + cc;
        kvv = MK[base];
        vvv = MV[base];
      }
      E[r][cc]  = __expf(kvv * SCALE - gm);
      Vv[r][cc] = vvv;
    }
    __syncthreads();
#pragma unroll
    for (int r = 0; r < 16; ++r) {
      const float vv = Vv[r][e];
#pragma unroll
      for (int j = 0; j < 16; ++j)
        acc[j] += E[r][dg * 16 + j] * vv;
    }
    __syncthreads();
  }
#pragma unroll
  for (int j = 0; j < 16; ++j)
    pkv[(((long)bh * NCHUNK + c) * 64 + dg * 16 + j) * 64 + e] = acc[j];
}

// ---------------- P4: reduce chunk kv, normalize, write kvT[bh][e][d] f32.
__global__ __launch_bounds__(256) void reduce_kv(const float* __restrict__ pkv,
                                                 const float* __restrict__ gZ,
                                                 float* __restrict__ kvT) {
  const int idx = blockIdx.x * 256 + threadIdx.x;  // bh*4096 + d*64 + e
  const int bh = idx >> 12, de = idx & 4095, d = de >> 6, e = de & 63;
  float s = 0.f;
#pragma unroll
  for (int c = 0; c < NCHUNK; ++c) s += pkv[((long)bh * NCHUNK + c) * 4096 + de];
  kvT[(long)bh * 4096 + e * 64 + d] = s / gZ[bh * 64 + d];
}

// ---------------- Z: beta = softmax_dk(q) from f32 q; z = beta @ kv (kv hi/lo split).
__global__ __launch_bounds__(256) void beta_z(const float* __restrict__ qf,
                                              const float* __restrict__ kvT,
                                              float* __restrict__ y) {
  const int bh = blockIdx.y, b = bh >> 4, h = bh & 15;
  const int t0 = blockIdx.x * 256;
  const int tid = threadIdx.x;
  const int w = tid >> 6, lane = tid & 63;
  __shared__ unsigned short beta_s[256 * 72];
  __shared__ unsigned short kvh_s[64 * 72], kvl_s[64 * 72];

  // phase A: one token per thread — softmax over dk=64 in f32
  {
    const float* qp = qf + ((long)(b * NSEQ) + t0 + tid) * DMODEL + h * DK;
    float vals[64];
#pragma unroll
    for (int i = 0; i < 16; ++i) {
      const float4v r = *(const float4v*)(qp + i * 4);
#pragma unroll
      for (int j = 0; j < 4; ++j) vals[i * 4 + j] = r[j];
    }
    float mx = vals[0];
#pragma unroll
    for (int i = 1; i < 64; ++i) mx = fmaxf(mx, vals[i]);
    float sum = 0.f;
#pragma unroll
    for (int i = 0; i < 64; ++i) { vals[i] = __expf(vals[i] - mx); sum += vals[i]; }
    const float inv = 1.f / sum;
#pragma unroll
    for (int i = 0; i < 64; ++i) beta_s[tid * 72 + i] = f2b(vals[i] * inv);
  }
  // stage kvT slice (f32) into hi/lo bf16 planes
  for (int c = tid; c < 4096; c += 256) {
    const float v = kvT[((long)bh << 12) + c];
    const int e = c >> 6, d = c & 63;
    unsigned short hh, ll;
    split1(v, hh, ll);
    kvh_s[e * 72 + d] = hh;
    kvl_s[e * 72 + d] = ll;
  }
  __syncthreads();

  // phase B: MFMA — z[64 tok x 64 e] per wave, 2-term kv split
  float4v acc[4][4];
#pragma unroll
  for (int i = 0; i < 4; ++i)
#pragma unroll
    for (int j = 0; j < 4; ++j) acc[i][j] = (float4v){0.f, 0.f, 0.f, 0.f};
  const int m15 = lane & 15, q8 = (lane >> 4) * 8;
#pragma unroll
  for (int k0 = 0; k0 < 64; k0 += 32) {
    short8 af[4], bh_[4], bl_[4];
#pragma unroll
    for (int t = 0; t < 4; ++t) {
      af[t]  = *(const short8*)&beta_s[(w * 64 + t * 16 + m15) * 72 + k0 + q8];
      bh_[t] = *(const short8*)&kvh_s[(t * 16 + m15) * 72 + k0 + q8];
      bl_[t] = *(const short8*)&kvl_s[(t * 16 + m15) * 72 + k0 + q8];
    }
#pragma unroll
    for (int mt = 0; mt < 4; ++mt)
#pragma unroll
      for (int nt = 0; nt < 4; ++nt) {
        acc[mt][nt] = __builtin_amdgcn_mfma_f32_16x16x32_bf16(af[mt], bh_[nt], acc[mt][nt], 0, 0, 0);
        acc[mt][nt] = __builtin_amdgcn_mfma_f32_16x16x32_bf16(af[mt], bl_[nt], acc[mt][nt], 0, 0, 0);
      }
  }
  const long ybase = ((long)b * NSEQ) * DMODEL + (long)h * DK;
  const int q4 = (lane >> 4) * 4;
#pragma unroll
  for (int mt = 0; mt < 4; ++mt)
#pragma unroll
    for (int nt = 0; nt < 4; ++nt)
#pragma unroll
      for (int i = 0; i < 4; ++i) {
        const int t = t0 + w * 64 + mt * 16 + q4 + i;
        y[ybase + (long)t * DMODEL + nt * 16 + m15] = acc[mt][nt][i];
      }
}

extern "C" void kernel_launch(void* const* d_in, const int* in_sizes, int n_in,
                              void* d_out, int out_size, void* d_ws, size_t ws_size,
                              hipStream_t stream) {
  const float* Q  = (const float*)d_in[0];
  const float* Kk = (const float*)d_in[1];
  const float* V  = (const float*)d_in[2];
  const float* WQ = (const float*)d_in[3];
  const float* WK = (const float*)d_in[4];
  const float* WV = (const float*)d_in[5];
  const float* WO = (const float*)d_in[6];
  const float* MK = (const float*)d_in[7];
  const float* MV = (const float*)d_in[8];

  char* ws = (char*)d_ws;
  // layout: qf f32 [0,64M) | kf f32 [64M,128M) (yf aliases) | vf f32 [128M,192M)
  //         W hi/lo 8x2M [192M,208M) | stats/pkv/kvT @208M
  float* qf = (float*)(ws);
  float* kf = (float*)(ws + 67108864);
  float* vf = (float*)(ws + 134217728);
  float* yf = (float*)(ws + 67108864);  // alias kf (dead after partial_kv)
  unsigned short* WQh = (unsigned short*)(ws + 201326592);
  unsigned short* WQl = (unsigned short*)(ws + 201326592 + 2097152);
  unsigned short* WKh = (unsigned short*)(ws + 201326592 + 4194304);
  unsigned short* WKl = (unsigned short*)(ws + 201326592 + 6291456);
  unsigned short* WVh = (unsigned short*)(ws + 201326592 + 8388608);
  unsigned short* WVl = (unsigned short*)(ws + 201326592 + 10485760);
  unsigned short* WOh = (unsigned short*)(ws + 201326592 + 12582912);
  unsigned short* WOl = (unsigned short*)(ws + 201326592 + 14680064);
  const long S = 218103808;
  float* pmax = (float*)(ws + S);
  float* psum = (float*)(ws + S + 131072);
  float* gmax = (float*)(ws + S + 262144);
  float* gZ   = (float*)(ws + S + 278528);
  float* pkv  = (float*)(ws + S + 294912);
  float* kvT  = (float*)(ws + S + 8683520);

  const dim3 blk(256);
  const int M = 16384, N = 1024, K = 1024;

  cvt_split<<<512, blk, 0, stream>>>(WQ, WQh, WQl, DMODEL * DMODEL);
  cvt_split<<<512, blk, 0, stream>>>(WK, WKh, WKl, DMODEL * DMODEL);
  cvt_split<<<512, blk, 0, stream>>>(WV, WVh, WVl, DMODEL * DMODEL);
  cvt_split<<<512, blk, 0, stream>>>(WO, WOh, WOl, DMODEL * DMODEL);

  gemm_split<<<dim3(8, 128, 1), blk, 0, stream>>>(Q,  WQh, WQl, qf, M, N, K);
  gemm_split<<<dim3(8, 128, 1), blk, 0, stream>>>(Kk, WKh, WKl, kf, M, N, K);
  gemm_split<<<dim3(8, 128, 1), blk, 0, stream>>>(V,  WVh, WVl, vf, M, N, K);

  col_stats<<<dim3(64, 8), blk, 0, stream>>>(kf, MK, pmax, psum);
  combine_stats<<<16, blk, 0, stream>>>(pmax, psum, gmax, gZ);
  partial_kv<<<dim3(64, 8), blk, 0, stream>>>(kf, vf, MK, MV, gmax, pkv);
  reduce_kv<<<1024, blk, 0, stream>>>(pkv, gZ, kvT);
  beta_z<<<dim3(16, 64), blk, 0, stream>>>(qf, kvT, yf);

  gemm_split<<<dim3(8, 128, 1), blk, 0, stream>>>(yf, WOh, WOl, (float*)d_out, M, N, K);
}

// Round 4
// 711.083 us; speedup vs baseline: 1.2988x; 1.2988x over previous
//
#include <hip/hip_runtime.h>
#include <stdint.h>

typedef __attribute__((ext_vector_type(8))) short short8;
typedef __attribute__((ext_vector_type(4))) float float4v;
typedef __attribute__((ext_vector_type(4))) unsigned int uint4v;

#define NSEQ   4096
#define DMODEL 1024
#define NHEAD  16
#define DK     64
#define NP     512
#define MTOT   4608
#define CHUNK  576
#define NCHUNK 8
#define SCALE  2.8284271247461903f   // 64^0.25

__device__ __forceinline__ float b2f(unsigned short u) {
  union { unsigned u; float f; } x; x.u = ((unsigned)u) << 16; return x.f;
}
__device__ __forceinline__ unsigned short f2b(float f) {
  union { float f; unsigned u; } x; x.f = f;
  unsigned r = x.u + 0x7fffu + ((x.u >> 16) & 1u);
  return (unsigned short)(r >> 16);
}
__device__ __forceinline__ unsigned pack2(float lo, float hi) {
  union { float f; unsigned u; } a, b; a.f = lo; b.f = hi;
  return ((a.u + 0x8000u) >> 16) | ((b.u + 0x8000u) & 0xffff0000u);
}
__device__ __forceinline__ void split1(float x, unsigned short& h, unsigned short& l) {
  h = f2b(x);
  l = f2b(x - b2f(h));
}
__device__ __forceinline__ void gload16(const void* g, void* l) {
  __builtin_amdgcn_global_load_lds((const __attribute__((address_space(1))) void*)g,
                                   (__attribute__((address_space(3))) void*)l,
                                   16, 0, 0);
}

// XCD-aware swizzle: lin%8 = hw XCD (round-robin); each XCD covers 16
// contiguous row-strips, col fastest -> A strip fetched once per XCD L2.
__device__ __forceinline__ void swz(int lin, long& brow, long& bcol) {
  brow = (long)(((lin & 7) << 4) | (lin >> 6)) * 128;
  bcol = (long)((lin >> 3) & 7) * 128;
}

// ---------------- weight f32 -> (hi, lo) bf16 split
__global__ __launch_bounds__(256) void cvt_split(const float* __restrict__ s,
                                                 unsigned short* __restrict__ hi,
                                                 unsigned short* __restrict__ lo, int n) {
  const int i = (blockIdx.x * 256 + threadIdx.x) * 8;
  if (i + 8 > n) return;
  float4v x0 = *(const float4v*)(s + i);
  float4v x1 = *(const float4v*)(s + i + 4);
  unsigned short h[8], l[8];
#pragma unroll
  for (int j = 0; j < 4; ++j) split1(x0[j], h[j], l[j]);
#pragma unroll
  for (int j = 0; j < 4; ++j) split1(x1[j], h[4 + j], l[4 + j]);
  uint4v ph, pl;
#pragma unroll
  for (int j = 0; j < 4; ++j) {
    ph[j] = (unsigned)h[2 * j] | ((unsigned)h[2 * j + 1] << 16);
    pl[j] = (unsigned)l[2 * j] | ((unsigned)l[2 * j + 1] << 16);
  }
  *(uint4v*)(hi + i) = ph;
  *(uint4v*)(lo + i) = pl;
}

// ---------------- GEMM: C[M,N] = A[M,K](f32) @ B[N,K]^T (B pre-split bf16 hi/lo).
// TERMS: 1 = Ah*Bh, 2 = +Al*Bh, 3 = +Ah*Bl. 128x128 tile, BK=32.
template<int TERMS, int BF16OUT>
__global__ __launch_bounds__(256, 2) void gemm_af32(const float* __restrict__ A,
                                                    const unsigned short* __restrict__ Bh,
                                                    const unsigned short* __restrict__ Bl,
                                                    void* __restrict__ Cv,
                                                    int N, int K) {
  __shared__ unsigned short Ash[4096];
  __shared__ unsigned short Bsh[4096];
  __shared__ unsigned short Asl[(TERMS >= 2) ? 4096 : 8];
  __shared__ unsigned short Bsl[(TERMS >= 3) ? 4096 : 8];
  const int tid = threadIdx.x;
  const int w = tid >> 6, lane = tid & 63;
  const int wr = w >> 1, wc = w & 1;
  long brow, bcol; swz(blockIdx.x, brow, bcol);

  const int rowA0 = w * 16 + (lane >> 2);
  const int colk  = (lane & 3) * 8;
  const float* Ag0 = A + (brow + rowA0) * (long)K + colk;
  const float* Ag1 = Ag0 + 64L * K;
  unsigned short* Ah0 = &Ash[tid * 8];
  unsigned short* Ah1 = &Ash[2048 + tid * 8];
  unsigned short* Al0 = &Asl[tid * 8];
  unsigned short* Al1 = &Asl[2048 + tid * 8];

  const int r0 = tid >> 2;
  const int kc = (tid & 3) * 8;
  const unsigned short* Bhg0 = Bh + (bcol + r0) * (long)K + kc;
  const unsigned short* Bhg1 = Bhg0 + 64L * K;
  const unsigned short* Blg0 = Bl + (bcol + r0) * (long)K + kc;
  const unsigned short* Blg1 = Blg0 + 64L * K;
  unsigned short* Bh0 = &Bsh[w * 512];
  unsigned short* Bl0 = &Bsl[w * 512];

  float4v acc[4][4];
#pragma unroll
  for (int i = 0; i < 4; ++i)
#pragma unroll
    for (int j = 0; j < 4; ++j) acc[i][j] = (float4v){0.f, 0.f, 0.f, 0.f};

  const int m15 = lane & 15, q8 = (lane >> 4) * 8;

  for (int k0 = 0; k0 < K; k0 += 32) {
    gload16(Bhg0 + k0, Bh0);
    gload16(Bhg1 + k0, Bh0 + 2048);
    if constexpr (TERMS >= 3) {
      gload16(Blg0 + k0, Bl0);
      gload16(Blg1 + k0, Bl0 + 2048);
    }
    {
      float4v a0 = *(const float4v*)(Ag0 + k0);
      float4v a1 = *(const float4v*)(Ag0 + k0 + 4);
      float4v c0 = *(const float4v*)(Ag1 + k0);
      float4v c1 = *(const float4v*)(Ag1 + k0 + 4);
      if constexpr (TERMS >= 2) {
        unsigned short h[16], l[16];
#pragma unroll
        for (int j = 0; j < 4; ++j) { split1(a0[j], h[j], l[j]); split1(a1[j], h[4 + j], l[4 + j]); }
#pragma unroll
        for (int j = 0; j < 4; ++j) { split1(c0[j], h[8 + j], l[8 + j]); split1(c1[j], h[12 + j], l[12 + j]); }
        uint4v pah, pal, pch, pcl;
#pragma unroll
        for (int j = 0; j < 4; ++j) {
          pah[j] = (unsigned)h[2 * j] | ((unsigned)h[2 * j + 1] << 16);
          pal[j] = (unsigned)l[2 * j] | ((unsigned)l[2 * j + 1] << 16);
          pch[j] = (unsigned)h[8 + 2 * j] | ((unsigned)h[8 + 2 * j + 1] << 16);
          pcl[j] = (unsigned)l[8 + 2 * j] | ((unsigned)l[8 + 2 * j + 1] << 16);
        }
        *(uint4v*)Ah0 = pah; *(uint4v*)Al0 = pal;
        *(uint4v*)Ah1 = pch; *(uint4v*)Al1 = pcl;
      } else {
        uint4v pah, pch;
        pah[0] = pack2(a0[0], a0[1]); pah[1] = pack2(a0[2], a0[3]);
        pah[2] = pack2(a1[0], a1[1]); pah[3] = pack2(a1[2], a1[3]);
        pch[0] = pack2(c0[0], c0[1]); pch[1] = pack2(c0[2], c0[3]);
        pch[2] = pack2(c1[0], c1[1]); pch[3] = pack2(c1[2], c1[3]);
        *(uint4v*)Ah0 = pah;
        *(uint4v*)Ah1 = pch;
      }
    }
    __syncthreads();
    short8 ah[4], al[4], bh[4], bl[4];
#pragma unroll
    for (int t = 0; t < 4; ++t) {
      const int ar = (wr * 64 + t * 16 + m15) * 32 + q8;
      const int br = (wc * 64 + t * 16 + m15) * 32 + q8;
      ah[t] = *(const short8*)&Ash[ar];
      bh[t] = *(const short8*)&Bsh[br];
      if constexpr (TERMS >= 2) al[t] = *(const short8*)&Asl[ar];
      if constexpr (TERMS >= 3) bl[t] = *(const short8*)&Bsl[br];
    }
#pragma unroll
    for (int mt = 0; mt < 4; ++mt)
#pragma unroll
      for (int nt = 0; nt < 4; ++nt) {
        acc[mt][nt] = __builtin_amdgcn_mfma_f32_16x16x32_bf16(ah[mt], bh[nt], acc[mt][nt], 0, 0, 0);
        if constexpr (TERMS >= 2)
          acc[mt][nt] = __builtin_amdgcn_mfma_f32_16x16x32_bf16(al[mt], bh[nt], acc[mt][nt], 0, 0, 0);
        if constexpr (TERMS >= 3)
          acc[mt][nt] = __builtin_amdgcn_mfma_f32_16x16x32_bf16(ah[mt], bl[nt], acc[mt][nt], 0, 0, 0);
      }
    __syncthreads();
  }

  const long col  = bcol + wc * 64 + m15;
  const long rowb = brow + wr * 64 + (lane >> 4) * 4;
  if constexpr (BF16OUT) {
    unsigned short* C = (unsigned short*)Cv;
#pragma unroll
    for (int mt = 0; mt < 4; ++mt)
#pragma unroll
      for (int nt = 0; nt < 4; ++nt)
#pragma unroll
        for (int i = 0; i < 4; ++i)
          C[(rowb + mt * 16 + i) * (long)N + col + nt * 16] = f2b(acc[mt][nt][i]);
  } else {
    float* C = (float*)Cv;
#pragma unroll
    for (int mt = 0; mt < 4; ++mt)
#pragma unroll
      for (int nt = 0; nt < 4; ++nt)
#pragma unroll
        for (int i = 0; i < 4; ++i)
          C[(rowb + mt * 16 + i) * (long)N + col + nt * 16] = acc[mt][nt][i];
  }
}

// ---------------- pure-bf16 NT GEMM (m97 path) for the output projection.
__global__ __launch_bounds__(256, 2) void gemm_bt(const unsigned short* __restrict__ A,
                                                  const unsigned short* __restrict__ B,
                                                  float* __restrict__ C,
                                                  int N, int K) {
  __shared__ unsigned short As[4096];
  __shared__ unsigned short Bs[4096];
  const int tid = threadIdx.x;
  const int w = tid >> 6, lane = tid & 63;
  const int wr = w >> 1, wc = w & 1;
  long brow, bcol; swz(blockIdx.x, brow, bcol);

  const int r0 = tid >> 2;
  const int kc = (tid & 3) * 8;
  const unsigned short* Ag0 = A + (brow + r0) * (long)K + kc;
  const unsigned short* Ag1 = Ag0 + 64L * K;
  const unsigned short* Bg0 = B + (bcol + r0) * (long)K + kc;
  const unsigned short* Bg1 = Bg0 + 64L * K;
  unsigned short* As0 = &As[w * 512];
  unsigned short* Bs0 = &Bs[w * 512];

  float4v acc[4][4];
#pragma unroll
  for (int i = 0; i < 4; ++i)
#pragma unroll
    for (int j = 0; j < 4; ++j) acc[i][j] = (float4v){0.f, 0.f, 0.f, 0.f};

  const int m15 = lane & 15, q8 = (lane >> 4) * 8;

  for (int k0 = 0; k0 < K; k0 += 32) {
    gload16(Ag0 + k0, As0);
    gload16(Ag1 + k0, As0 + 2048);
    gload16(Bg0 + k0, Bs0);
    gload16(Bg1 + k0, Bs0 + 2048);
    __syncthreads();
    short8 af[4], bfr[4];
#pragma unroll
    for (int t = 0; t < 4; ++t) {
      af[t]  = *(const short8*)&As[(wr * 64 + t * 16 + m15) * 32 + q8];
      bfr[t] = *(const short8*)&Bs[(wc * 64 + t * 16 + m15) * 32 + q8];
    }
#pragma unroll
    for (int mt = 0; mt < 4; ++mt)
#pragma unroll
      for (int nt = 0; nt < 4; ++nt)
        acc[mt][nt] = __builtin_amdgcn_mfma_f32_16x16x32_bf16(af[mt], bfr[nt], acc[mt][nt], 0, 0, 0);
    __syncthreads();
  }

  const long col  = bcol + wc * 64 + m15;
  const long rowb = brow + wr * 64 + (lane >> 4) * 4;
#pragma unroll
  for (int mt = 0; mt < 4; ++mt)
#pragma unroll
    for (int nt = 0; nt < 4; ++nt)
#pragma unroll
      for (int i = 0; i < 4; ++i)
        C[(rowb + mt * 16 + i) * (long)N + col + nt * 16] = acc[mt][nt][i];
}

// ---------------- P1: per-(b,h,d) online max/sumexp over m-chunk (f32 k).
__global__ __launch_bounds__(256) void col_stats(const float* __restrict__ kf,
                                                 const float* __restrict__ MK,
                                                 float* __restrict__ pmax,
                                                 float* __restrict__ psum) {
  const int bh = blockIdx.x, c = blockIdx.y;
  const int b = bh >> 4, h = bh & 15;
  const int d = threadIdx.x & 63, g = threadIdx.x >> 6;
  float mx = -1e30f, sm = 0.f;
  const int m0 = c * CHUNK;
  for (int i = g; i < CHUNK; i += 4) {
    const int m = m0 + i;
    float val;
    if (m < NSEQ) val = kf[((long)(b * NSEQ + m)) * DMODEL + h * DK + d];
    else          val = MK[((long)h * NP + (m - NSEQ)) * DK + d];
    const float x = val * SCALE;
    if (x > mx) { sm = sm * __expf(mx - x) + 1.f; mx = x; }
    else        { sm += __expf(x - mx); }
  }
  __shared__ float smx[4][64], ssm[4][64];
  smx[g][d] = mx; ssm[g][d] = sm;
  __syncthreads();
  if (g == 0) {
    float M = smx[0][d], S = ssm[0][d];
#pragma unroll
    for (int j = 1; j < 4; ++j) {
      const float m2 = smx[j][d], s2 = ssm[j][d];
      const float nm = fmaxf(M, m2);
      S = S * __expf(M - nm) + s2 * __expf(m2 - nm);
      M = nm;
    }
    pmax[(bh * NCHUNK + c) * 64 + d] = M;
    psum[(bh * NCHUNK + c) * 64 + d] = S;
  }
}

// ---------------- P2: combine chunk stats.
__global__ __launch_bounds__(256) void combine_stats(const float* __restrict__ pmax,
                                                     const float* __restrict__ psum,
                                                     float* __restrict__ gmax,
                                                     float* __restrict__ gZ) {
  const int idx = blockIdx.x * 256 + threadIdx.x;
  const int bh = idx >> 6, d = idx & 63;
  float M = -1e30f, S = 0.f;
#pragma unroll
  for (int c = 0; c < NCHUNK; ++c) {
    const float m2 = pmax[(bh * NCHUNK + c) * 64 + d];
    const float s2 = psum[(bh * NCHUNK + c) * 64 + d];
    const float nm = fmaxf(M, m2);
    S = S * __expf(M - nm) + s2 * __expf(m2 - nm);
    M = nm;
  }
  gmax[idx] = M;
  gZ[idx] = S;
}

// ---------------- P3: partial kv over chunk (f32 k, bf16 v).
__global__ __launch_bounds__(256) void partial_kv(const float* __restrict__ kf,
                                                  const unsigned short* __restrict__ vb,
                                                  const float* __restrict__ MK,
                                                  const float* __restrict__ MV,
                                                  const float* __restrict__ gmax,
                                                  float* __restrict__ pkv) {
  const int bh = blockIdx.x, c = blockIdx.y;
  const int b = bh >> 4, h = bh & 15;
  const int e = threadIdx.x & 63, dg = threadIdx.x >> 6;
  __shared__ float E[16][64], Vv[16][64];
  float acc[16];
#pragma unroll
  for (int j = 0; j < 16; ++j) acc[j] = 0.f;
  const int cc = e;
  const float gm = gmax[bh * 64 + cc];

  for (int t = 0; t < CHUNK / 16; ++t) {
    const int mt0 = c * CHUNK + t * 16;
#pragma unroll
    for (int i = 0; i < 4; ++i) {
      const int r = dg + 4 * i;
      const int m = mt0 + r;
      float kvv, vvv;
      if (m < NSEQ) {
        const long base = ((long)(b * NSEQ + m)) * DMODEL + h * DK + cc;
        kvv = kf[base];
        vvv = b2f(vb[base]);
      } else {
        const long base = ((long)h * NP + (m - NSEQ)) * DK + cc;
        kvv = MK[base];
        vvv = MV[base];
      }
      E[r][cc]  = __expf(kvv * SCALE - gm);
      Vv[r][cc] = vvv;
    }
    __syncthreads();
#pragma unroll
    for (int r = 0; r < 16; ++r) {
      const float vv = Vv[r][e];
#pragma unroll
      for (int j = 0; j < 16; ++j)
        acc[j] += E[r][dg * 16 + j] * vv;
    }
    __syncthreads();
  }
#pragma unroll
  for (int j = 0; j < 16; ++j)
    pkv[(((long)bh * NCHUNK + c) * 64 + dg * 16 + j) * 64 + e] = acc[j];
}

// ---------------- P4: reduce chunk kv, normalize, write kvT[bh][e][d] f32.
__global__ __launch_bounds__(256) void reduce_kv(const float* __restrict__ pkv,
                                                 const float* __restrict__ gZ,
                                                 float* __restrict__ kvT) {
  const int idx = blockIdx.x * 256 + threadIdx.x;
  const int bh = idx >> 12, de = idx & 4095, d = de >> 6, e = de & 63;
  float s = 0.f;
#pragma unroll
  for (int c = 0; c < NCHUNK; ++c) s += pkv[((long)bh * NCHUNK + c) * 4096 + de];
  kvT[(long)bh * 4096 + e * 64 + d] = s / gZ[bh * 64 + d];
}

// ---------------- Z: beta = softmax_dk(q) (bf16 q); z = beta @ kv (kv f32, hi/lo split).
__global__ __launch_bounds__(256) void beta_z(const unsigned short* __restrict__ qb,
                                              const float* __restrict__ kvT,
                                              unsigned short* __restrict__ y) {
  const int bh = blockIdx.y, b = bh >> 4, h = bh & 15;
  const int t0 = blockIdx.x * 256;
  const int tid = threadIdx.x;
  const int w = tid >> 6, lane = tid & 63;
  __shared__ unsigned short beta_s[256 * 72];
  __shared__ unsigned short kvh_s[64 * 72], kvl_s[64 * 72];

  {
    const unsigned short* qp = qb + ((long)(b * NSEQ) + t0 + tid) * DMODEL + h * DK;
    float vals[64];
#pragma unroll
    for (int i = 0; i < 8; ++i) {
      const short8 r = *(const short8*)(qp + i * 8);
#pragma unroll
      for (int j = 0; j < 8; ++j) vals[i * 8 + j] = b2f((unsigned short)r[j]);
    }
    float mx = vals[0];
#pragma unroll
    for (int i = 1; i < 64; ++i) mx = fmaxf(mx, vals[i]);
    float sum = 0.f;
#pragma unroll
    for (int i = 0; i < 64; ++i) { vals[i] = __expf(vals[i] - mx); sum += vals[i]; }
    const float inv = 1.f / sum;
#pragma unroll
    for (int i = 0; i < 64; ++i) beta_s[tid * 72 + i] = f2b(vals[i] * inv);
  }
  for (int c = tid; c < 4096; c += 256) {
    const float v = kvT[((long)bh << 12) + c];
    const int e = c >> 6, d = c & 63;
    unsigned short hh, ll;
    split1(v, hh, ll);
    kvh_s[e * 72 + d] = hh;
    kvl_s[e * 72 + d] = ll;
  }
  __syncthreads();

  float4v acc[4][4];
#pragma unroll
  for (int i = 0; i < 4; ++i)
#pragma unroll
    for (int j = 0; j < 4; ++j) acc[i][j] = (float4v){0.f, 0.f, 0.f, 0.f};
  const int m15 = lane & 15, q8 = (lane >> 4) * 8;
#pragma unroll
  for (int k0 = 0; k0 < 64; k0 += 32) {
    short8 af[4], bh_[4], bl_[4];
#pragma unroll
    for (int t = 0; t < 4; ++t) {
      af[t]  = *(const short8*)&beta_s[(w * 64 + t * 16 + m15) * 72 + k0 + q8];
      bh_[t] = *(const short8*)&kvh_s[(t * 16 + m15) * 72 + k0 + q8];
      bl_[t] = *(const short8*)&kvl_s[(t * 16 + m15) * 72 + k0 + q8];
    }
#pragma unroll
    for (int mt = 0; mt < 4; ++mt)
#pragma unroll
      for (int nt = 0; nt < 4; ++nt) {
        acc[mt][nt] = __builtin_amdgcn_mfma_f32_16x16x32_bf16(af[mt], bh_[nt], acc[mt][nt], 0, 0, 0);
        acc[mt][nt] = __builtin_amdgcn_mfma_f32_16x16x32_bf16(af[mt], bl_[nt], acc[mt][nt], 0, 0, 0);
      }
  }
  const long ybase = ((long)b * NSEQ) * DMODEL + (long)h * DK;
  const int q4 = (lane >> 4) * 4;
#pragma unroll
  for (int mt = 0; mt < 4; ++mt)
#pragma unroll
    for (int nt = 0; nt < 4; ++nt)
#pragma unroll
      for (int i = 0; i < 4; ++i) {
        const int t = t0 + w * 64 + mt * 16 + q4 + i;
        y[ybase + (long)t * DMODEL + nt * 16 + m15] = f2b(acc[mt][nt][i]);
      }
}

extern "C" void kernel_launch(void* const* d_in, const int* in_sizes, int n_in,
                              void* d_out, int out_size, void* d_ws, size_t ws_size,
                              hipStream_t stream) {
  const float* Q  = (const float*)d_in[0];
  const float* Kk = (const float*)d_in[1];
  const float* V  = (const float*)d_in[2];
  const float* WQ = (const float*)d_in[3];
  const float* WK = (const float*)d_in[4];
  const float* WV = (const float*)d_in[5];
  const float* WO = (const float*)d_in[6];
  const float* MK = (const float*)d_in[7];
  const float* MV = (const float*)d_in[8];

  char* ws = (char*)d_ws;
  // qb bf16 [0,32M) | kf f32 [32M,96M) (yb bf16 aliases [32M,64M) after partial_kv)
  // vb bf16 [96M,128M) | weights 16M @128M | stats/pkv/kvT @144M
  unsigned short* qb = (unsigned short*)(ws);
  float*          kf = (float*)(ws + 33554432);
  unsigned short* yb = (unsigned short*)(ws + 33554432);
  unsigned short* vb = (unsigned short*)(ws + 100663296);
  const long WB = 134217728;
  unsigned short* WQh = (unsigned short*)(ws + WB);
  unsigned short* WQl = (unsigned short*)(ws + WB + 2097152);
  unsigned short* WKh = (unsigned short*)(ws + WB + 4194304);
  unsigned short* WKl = (unsigned short*)(ws + WB + 6291456);
  unsigned short* WVh = (unsigned short*)(ws + WB + 8388608);
  unsigned short* WVl = (unsigned short*)(ws + WB + 10485760);
  unsigned short* WOh = (unsigned short*)(ws + WB + 12582912);
  unsigned short* WOl = (unsigned short*)(ws + WB + 14680064);
  const long S = 150994944;
  float* pmax = (float*)(ws + S);
  float* psum = (float*)(ws + S + 131072);
  float* gmax = (float*)(ws + S + 262144);
  float* gZ   = (float*)(ws + S + 278528);
  float* pkv  = (float*)(ws + S + 294912);
  float* kvT  = (float*)(ws + S + 8683520);

  const dim3 blk(256);
  const int N = 1024, K = 1024;

  cvt_split<<<512, blk, 0, stream>>>(WQ, WQh, WQl, DMODEL * DMODEL);
  cvt_split<<<512, blk, 0, stream>>>(WK, WKh, WKl, DMODEL * DMODEL);
  cvt_split<<<512, blk, 0, stream>>>(WV, WVh, WVl, DMODEL * DMODEL);
  cvt_split<<<512, blk, 0, stream>>>(WO, WOh, WOl, DMODEL * DMODEL);

  gemm_af32<1, 1><<<1024, blk, 0, stream>>>(Q,  WQh, WQl, (void*)qb, N, K);
  gemm_af32<3, 0><<<1024, blk, 0, stream>>>(Kk, WKh, WKl, (void*)kf, N, K);
  gemm_af32<1, 1><<<1024, blk, 0, stream>>>(V,  WVh, WVl, (void*)vb, N, K);

  col_stats<<<dim3(64, 8), blk, 0, stream>>>(kf, MK, pmax, psum);
  combine_stats<<<16, blk, 0, stream>>>(pmax, psum, gmax, gZ);
  partial_kv<<<dim3(64, 8), blk, 0, stream>>>(kf, vb, MK, MV, gmax, pkv);
  reduce_kv<<<1024, blk, 0, stream>>>(pkv, gZ, kvT);
  beta_z<<<dim3(16, 64), blk, 0, stream>>>(qb, kvT, yb);

  gemm_bt<<<1024, blk, 0, stream>>>(yb, WOh, (float*)d_out, N, K);
}